// Round 1
// baseline (29709.390 us; speedup 1.0000x reference)
//
#include <hip/hip_runtime.h>
#include <stdint.h>
#include <stddef.h>

// ---------------- problem constants ----------------
#define T_ 1024
#define B_ 64
#define W_ 512
// layers L = 2

// ---------------- ws layout (bytes) ----------------
#define WS_FLAGS   0        // u32: resets-type evidence bits
#define WS_VOTES   4        // u32: ins bf16 exponent votes
#define WS_MODEF   8        // u32: 0=f32 inputs, 1=bf16 inputs
#define WS_MODER   12       // u32: resets mode 0=i32 1=u8 2=f32 3=bf16
#define WS_ABORT   16       // u32: spin abort valve
#define WS_ROOT0   256      // u32 root barrier counter, layer 0
#define WS_ROOT1   320      // u32 root barrier counter, layer 1
#define WS_GRP     384      // u32 [2][8] group counters, stride 64 B (ends 1408)
#define WS_RESETS  4096     // u8[65536]
#define WS_RING0   131072   // bf16 [8][64][512]  = 524288 B
#define WS_RING1   655360   // bf16 [8][64][512]  = 524288 B
#define WS_WPACK   1179648  // bf16 packed weights: [2][32][96][64][8] = 6291456 B
#define WS_NEEDED  (WS_WPACK + 6291456)

using v8s = __attribute__((ext_vector_type(8))) short;
using v4f = __attribute__((ext_vector_type(4))) float;

__device__ __forceinline__ uint16_t f2bf(float f) {
  uint32_t x = __float_as_uint(f);
  uint32_t r = (x + 0x7FFFu + ((x >> 16) & 1u)) >> 16;
  return (uint16_t)r;
}
__device__ __forceinline__ float bf2f(uint16_t u) {
  return __uint_as_float(((uint32_t)u) << 16);
}
__device__ __forceinline__ v8s ld_v8s(const uint16_t* p) {
  return *(const v8s*)p;
}
__device__ __forceinline__ v8s cvt8(const float* p) {
  v8s o;
#pragma unroll
  for (int j = 0; j < 8; ++j) o[j] = (short)f2bf(p[j]);
  return o;
}

// ---------------- kernel 1: dtype detection ----------------
// resets evidence bits: 1=bf16-definite, 2=u8-pattern, 4=word 0x3F800000, 8=word 1
__global__ void k_detect(const uint32_t* rst, const uint32_t* insw,
                         uint32_t* flags, uint32_t* votes) {
  int i = blockIdx.x * 256 + threadIdx.x;  // 16384 threads
  uint32_t w = rst[i];
  uint32_t f = 0;
  if (w == 0x3F803F80u || w == 0x00003F80u) f |= 1u;
  if ((w & 0xFEFEFEFEu) == 0u && (w & 0xFFFFFF00u) != 0u) f |= 2u;
  if (w == 0x3F800000u) f |= 4u;
  if (w == 1u) f |= 8u;
  if (f) atomicOr(flags, f);
  if (i < 4096) {
    uint32_t b7 = (insw[i] >> 8) & 0x7Fu;  // bf16-lo exponent field if packed bf16
    if (b7 >= 0x3Au && b7 <= 0x41u) atomicAdd(votes, 1u);
  }
}

// ---------------- kernel 2: init (mode resolve, resets normalize, zero rings) ----
__global__ void k_init(const uint8_t* rst_raw, uint8_t* ws8) {
  int tid = blockIdx.x * 256 + threadIdx.x;  // 262144 threads
  uint32_t fl = *(const uint32_t*)(ws8 + WS_FLAGS);
  uint32_t vt = *(const uint32_t*)(ws8 + WS_VOTES);
  int modeF = (vt > 2048u) ? 1 : 0;
  int modeR;
  if (fl & 1u) modeR = 3;
  else if (fl & 2u) modeR = 1;
  else if (fl & 4u) modeR = modeF ? 3 : 2;
  else modeR = 0;
  if (tid == 0) {
    *(uint32_t*)(ws8 + WS_MODEF) = (uint32_t)modeF;
    *(uint32_t*)(ws8 + WS_MODER) = (uint32_t)modeR;
  }
  // zero both rings (1 MB total = 262144 u32 words)
  ((uint32_t*)(ws8 + WS_RING0))[tid] = 0u;
  if (tid < 65536) {
    bool v;
    if (modeR == 1)      v = rst_raw[tid] != 0;
    else if (modeR == 3) v = ((const uint16_t*)rst_raw)[tid] != 0;
    else                 v = ((const uint32_t*)rst_raw)[tid] != 0u;
    ws8[WS_RESETS + tid] = v ? 1 : 0;
  }
}

// ---------------- kernel 3: weight prepack into B-fragment order ----------------
// dest: [l][g][fragrow 0..95][lane 0..63][j 0..7] bf16
// fragrow: 0..31 = r-gate (K-concat 1024), 32..63 = z-gate, 64..79 = inn (Wi only),
//          80..95 = hn (Wh only).  B[k][n]: n = lane&15, k = kc*32 + (lane>>4)*8 + j
__global__ void k_prepack(const float* w32i, const uint16_t* w16i,
                          const float* w32h, const uint16_t* w16h, uint8_t* ws8) {
  int tid = blockIdx.x * 256 + threadIdx.x;  // 393216 threads
  int lane = tid & 63;
  int fragrow = (tid >> 6) % 96;
  int lg = tid / (96 * 64);  // 0..63
  int l = lg >> 5, g = lg & 31;
  int modeF = (int)*(const uint32_t*)(ws8 + WS_MODEF);
  int cg, kc;
  if (fragrow < 32)      { cg = 0; kc = fragrow; }
  else if (fragrow < 64) { cg = 1; kc = fragrow - 32; }
  else if (fragrow < 80) { cg = 2; kc = fragrow - 64; }
  else                   { cg = 3; kc = fragrow - 80; }
  int n = lane & 15, quad = lane >> 4;
  uint16_t* dst = (uint16_t*)(ws8 + WS_WPACK) + ((size_t)(lg * 96 + fragrow) * 64 + lane) * 8;
#pragma unroll
  for (int j = 0; j < 8; ++j) {
    int k = kc * 32 + quad * 8 + j;
    int col, kk;
    bool useWi;
    if (cg == 0)      { col = g * 16 + n;        useWi = (k < 512); kk = k & 511; }
    else if (cg == 1) { col = 512 + g * 16 + n;  useWi = (k < 512); kk = k & 511; }
    else if (cg == 2) { col = 1024 + g * 16 + n; useWi = true;      kk = k; }
    else              { col = 1024 + g * 16 + n; useWi = false;     kk = k; }
    size_t si = ((size_t)l * 512 + kk) * 1536 + col;
    uint16_t v;
    if (modeF) v = useWi ? w16i[si] : w16h[si];
    else       v = f2bf(useWi ? w32i[si] : w32h[si]);
    dst[j] = v;
  }
}

// ---------------- spin helper ----------------
__device__ __forceinline__ void spin_ge(uint32_t* p, int need, uint32_t* abortf) {
  if (need <= 0) return;
  int polls = 0;
  while ((int)__hip_atomic_load(p, __ATOMIC_RELAXED, __HIP_MEMORY_SCOPE_AGENT) < need) {
    __builtin_amdgcn_s_sleep(1);
    if ((++polls & 255) == 0) {
      if (__hip_atomic_load(abortf, __ATOMIC_RELAXED, __HIP_MEMORY_SCOPE_AGENT)) return;
      if (polls > (1 << 22)) {
        __hip_atomic_store(abortf, 1u, __ATOMIC_RELAXED, __HIP_MEMORY_SCOPE_AGENT);
        return;
      }
    }
  }
}

// ---------------- kernel 4: persistent pipelined GRU ----------------
// grid 256 = 2 layers x 32 col-slices x 4 row-tiles. block 256 (4 waves).
// wave 0: r-gate (K=1024), wave 1: z-gate (K=1024), wave 2: inn (K=512, x),
// wave 3: hn (K=512, h) + epilogue owner (holds fp32 h master).
__launch_bounds__(256, 1)
__global__ void k_gru(const uint16_t* ins16, const float* ins32,
                      const float* bi32, const uint16_t* bi16,
                      const float* bhn32, const uint16_t* bhn16,
                      float* out32, uint16_t* out16, uint8_t* ws8) {
  const int tid = threadIdx.x;
  const int wave = tid >> 6, lane = tid & 63;
  const int quad = lane >> 4, l16 = lane & 15;
  const int bid = (int)blockIdx.x;
  const int l = bid & 1;
  const int g = (bid >> 1) & 31;
  const int rt = (bid >> 6) & 3;
  const int wgid = rt * 32 + g;   // 0..127 within layer
  const int gid = wgid >> 4;      // 0..7

  uint32_t* rootS = (uint32_t*)(ws8 + (l ? WS_ROOT1 : WS_ROOT0));
  uint32_t* rootO = (uint32_t*)(ws8 + (l ? WS_ROOT0 : WS_ROOT1));
  uint32_t* grp   = (uint32_t*)(ws8 + WS_GRP + (size_t)(l * 8 + gid) * 64);
  uint32_t* abortf = (uint32_t*)(ws8 + WS_ABORT);
  const uint8_t* rst = ws8 + WS_RESETS;
  uint16_t* ring0 = (uint16_t*)(ws8 + WS_RING0);
  uint16_t* ring1 = (uint16_t*)(ws8 + WS_RING1);
  uint16_t* ringS = l ? ring1 : ring0;
  const uint16_t* wsw = (const uint16_t*)(ws8 + WS_WPACK);
  const int modeF = (int)*(volatile const uint32_t*)(ws8 + WS_MODEF);

  // --- load this wave's B fragments into registers (persistent) ---
  const int slice = l * 32 + g;
  const uint16_t* wbase = wsw + (size_t)slice * (96 * 64 * 8);
  const int nB = (wave < 2) ? 32 : 16;
  const int fb = (wave < 2) ? wave * 32 : 64 + (wave - 2) * 16;
  v8s Bv[32];
#pragma unroll
  for (int i = 0; i < 32; ++i)
    if (i < nB) Bv[i] = ld_v8s(wbase + ((size_t)(fb + i) * 64 + lane) * 8);

  // --- per-lane constants ---
  const int rowbase = rt * 16;
  const int bA = rowbase + l16;   // batch row this lane loads A for
  const int cC = g * 16 + l16;    // n-column this lane owns in C/epilogue
  float bir, biz, bin_, bh;
  if (modeF) {
    const uint16_t* b16 = bi16 + l * 1536;
    bir = bf2f(b16[cC]); biz = bf2f(b16[512 + cC]); bin_ = bf2f(b16[1024 + cC]);
    bh = bf2f(bhn16[l * 512 + cC]);
  } else {
    const float* b32 = bi32 + l * 1536;
    bir = b32[cC]; biz = b32[512 + cC]; bin_ = b32[1024 + cC];
    bh = bhn32[l * 512 + cC];
  }

  __shared__ float eb[3][64][4];
  float hm[4] = {0.f, 0.f, 0.f, 0.f};
  const int rEnd = l ? (T_ + 1) : T_;
  const v8s vzero = {0, 0, 0, 0, 0, 0, 0, 0};

  for (int r = 0; r < rEnd; ++r) {
    // ---- wait: own group finished r-1; other layer far enough along ----
    if (tid == 0) {
      spin_ge(rootS, r * 8, abortf);
      spin_ge(rootO, l ? r * 8 : (r - 6) * 8, abortf);
    }
    __syncthreads();
    __builtin_amdgcn_fence(__ATOMIC_ACQUIRE, "agent");

    const bool active = l ? (r > 0) : true;
    const int t = l ? (r - 1) : r;
    v4f acc = {0.f, 0.f, 0.f, 0.f};

    if (active) {
      const uint16_t* hprev = ringS + (size_t)((t - 1) & 7) * (B_ * W_);
      const uint16_t* xring = ring0 + (size_t)(t & 7) * (B_ * W_);
      const int rsA = (int)rst[t * 64 + bA];
      const int koq = quad * 8;

      if (wave < 2) {
#pragma unroll
        for (int kc = 0; kc < 16; ++kc) {  // x part, K 0..511
          v8s a;
          if (l)          a = ld_v8s(xring + bA * 512 + kc * 32 + koq);
          else if (modeF) a = ld_v8s(ins16 + ((size_t)t * 64 + bA) * 512 + kc * 32 + koq);
          else            a = cvt8(ins32 + ((size_t)t * 64 + bA) * 512 + kc * 32 + koq);
          acc = __builtin_amdgcn_mfma_f32_16x16x32_bf16(a, Bv[kc], acc, 0, 0, 0);
        }
#pragma unroll
        for (int kc = 0; kc < 16; ++kc) {  // h part, K 512..1023
          v8s a = ld_v8s(hprev + bA * 512 + kc * 32 + koq);
          if (rsA) a = vzero;
          acc = __builtin_amdgcn_mfma_f32_16x16x32_bf16(a, Bv[16 + kc], acc, 0, 0, 0);
        }
      } else if (wave == 2) {               // inn: x only
#pragma unroll
        for (int kc = 0; kc < 16; ++kc) {
          v8s a;
          if (l)          a = ld_v8s(xring + bA * 512 + kc * 32 + koq);
          else if (modeF) a = ld_v8s(ins16 + ((size_t)t * 64 + bA) * 512 + kc * 32 + koq);
          else            a = cvt8(ins32 + ((size_t)t * 64 + bA) * 512 + kc * 32 + koq);
          acc = __builtin_amdgcn_mfma_f32_16x16x32_bf16(a, Bv[kc], acc, 0, 0, 0);
        }
      } else {                              // hn: h only
#pragma unroll
        for (int kc = 0; kc < 16; ++kc) {
          v8s a = ld_v8s(hprev + bA * 512 + kc * 32 + koq);
          if (rsA) a = vzero;
          acc = __builtin_amdgcn_mfma_f32_16x16x32_bf16(a, Bv[kc], acc, 0, 0, 0);
        }
      }
      if (wave < 3) {
#pragma unroll
        for (int i = 0; i < 4; ++i) eb[wave][lane][i] = acc[i];
      }
    }
    __syncthreads();

    if (active && wave == 3) {
      uint16_t* hout = ringS + (size_t)(t & 7) * (B_ * W_);
#pragma unroll
      for (int i = 0; i < 4; ++i) {
        float ra = eb[0][lane][i], za = eb[1][lane][i], ia = eb[2][lane][i], ha = acc[i];
        float rg = 1.f / (1.f + __expf(-(ra + bir)));
        float zg = 1.f / (1.f + __expf(-(za + biz)));
        float narg = ia + bin_ + rg * (ha + bh);
        float e2 = __expf(-2.f * fabsf(narg));
        float ng = (1.f - e2) / (1.f + e2);
        ng = (narg < 0.f) ? -ng : ng;
        int b = rowbase + quad * 4 + i;
        float hp = rst[t * 64 + b] ? 0.f : hm[i];
        float hv = (1.f - zg) * ng + zg * hp;
        hm[i] = hv;
        hout[b * 512 + cC] = f2bf(hv);
        if (l) {  // ys output (layer-1 hidden)
          size_t off = (size_t)2 * B_ * W_ + ((size_t)t * 64 + b) * 512 + cC;
          if (modeF) out16[off] = f2bf(hv); else out32[off] = hv;
        }
        if (t == T_ - 1) {  // final carry
          size_t off = (size_t)l * (B_ * W_) + (size_t)b * 512 + cC;
          if (modeF) out16[off] = f2bf(hv); else out32[off] = hv;
        }
      }
    }
    __syncthreads();

    // ---- arrive: tree barrier (16 -> root) ----
    if (tid == 0) {
      __builtin_amdgcn_fence(__ATOMIC_RELEASE, "agent");
      uint32_t old = __hip_atomic_fetch_add(grp, 1u, __ATOMIC_ACQ_REL, __HIP_MEMORY_SCOPE_AGENT);
      if ((old & 15u) == 15u)
        __hip_atomic_fetch_add(rootS, 1u, __ATOMIC_RELEASE, __HIP_MEMORY_SCOPE_AGENT);
    }
  }
}

// ---------------- launcher ----------------
extern "C" void kernel_launch(void* const* d_in, const int* in_sizes, int n_in,
                              void* d_out, int out_size, void* d_ws, size_t ws_size,
                              hipStream_t stream) {
  (void)in_sizes; (void)n_in; (void)out_size;
  if (ws_size < (size_t)WS_NEEDED) return;  // visible failure rather than corruption

  const void* ins = d_in[0];
  const void* rst = d_in[1];
  const void* Wi  = d_in[2];
  const void* bi  = d_in[3];
  const void* Wh  = d_in[4];
  const void* bhn = d_in[5];
  uint8_t* ws8 = (uint8_t*)d_ws;

  hipMemsetAsync(d_ws, 0, 2048, stream);
  hipLaunchKernelGGL(k_detect, dim3(64), dim3(256), 0, stream,
                     (const uint32_t*)rst, (const uint32_t*)ins,
                     (uint32_t*)(ws8 + WS_FLAGS), (uint32_t*)(ws8 + WS_VOTES));
  hipLaunchKernelGGL(k_init, dim3(1024), dim3(256), 0, stream,
                     (const uint8_t*)rst, ws8);
  hipLaunchKernelGGL(k_prepack, dim3(1536), dim3(256), 0, stream,
                     (const float*)Wi, (const uint16_t*)Wi,
                     (const float*)Wh, (const uint16_t*)Wh, ws8);
  hipLaunchKernelGGL(k_gru, dim3(256), dim3(256), 0, stream,
                     (const uint16_t*)ins, (const float*)ins,
                     (const float*)bi, (const uint16_t*)bi,
                     (const float*)bhn, (const uint16_t*)bhn,
                     (float*)d_out, (uint16_t*)d_out, ws8);
}